// Round 10
// baseline (152.879 us; speedup 1.0000x reference)
//
#include <hip/hip_runtime.h>

#define BS 2
#define TS 128
#define DM 512
#define NH 8
#define DH 64
#define BN (BS*NH)            // 16

typedef __attribute__((ext_vector_type(8))) short short8;
typedef __attribute__((ext_vector_type(4))) float floatx4;

// ws layout (float element offsets). Total 4*SEG*4B = 2.1 MB (zb eliminated).
#define SEG (BN*TS*DH)                  // 131072
#define OFS_Q    0                      // fp32 [bn][s][h] (+bias)
#define OFS_VA   SEG                    // fp32 [bn][s][h]
#define OFS_VB   (2*SEG)                // fp32 [bn][s][h]
#define OFS_K1B  (3*SEG)                // bf16 [bn][s][h] (+bias), SEG/2 floats
#define OFS_K2B  (3*SEG + SEG/2)        // bf16 [bn][s][h] (+bias)

#define N_PROJ_JOBS 160

__device__ __forceinline__ unsigned short f2bf(float x) {
  unsigned u = __float_as_uint(x);
  u += 0x7fff + ((u >> 16) & 1);        // round-to-nearest-even
  return (unsigned short)(u >> 16);
}
__device__ __forceinline__ float bf2f(short v) {
  return __uint_as_float(((unsigned)(unsigned short)v) << 16);
}

struct __align__(16) ProjS { short xb[64][136]; short wbt[64][136]; }; // 34.8KB
struct __align__(16) AttnS {
  short Bh[128][72]; float Rs[128]; float Cp[4][128];
  float Cs[128]; float zpart[4][64]; float dpart[4];                   // 22.5KB
};

// ---------------------------------------------------------------------------
// proj kernel: identical to the R9 champion (112.1us config).
// ---------------------------------------------------------------------------
__global__ __launch_bounds__(256, 4) void proj_kernel(
    const float* __restrict__ x,   const float* __restrict__ Wk1,
    const float* __restrict__ Wk2, const float* __restrict__ Wq,
    const float* __restrict__ Wv12,const float* __restrict__ bk1,
    const float* __restrict__ bk2, const float* __restrict__ bq,
    float* __restrict__ ws)
{
  __shared__ ProjS u;
  int tid = threadIdx.x;
  int wv = tid >> 6, ln = tid & 63, q4 = ln >> 4, l15 = ln & 15;

  int t = blockIdx.x;
  int rt = t & 3; t >>= 2;
  int n  = t & 7; t >>= 3;
  int proj = t;                       // 0..4

  const float* W;
  switch (proj) {
    case 0:  W = Wk1 + n*DM*DH;  break;
    case 1:  W = Wk2 + n*DM*DH;  break;
    case 2:  W = Wq  + n*DM*DH;  break;
    case 3:  W = Wv12 + n*2*DM*DH;  break;
    default: W = Wv12 + n*2*DM*DH + DM*DH;  break;
  }

  floatx4 acc[4];
  #pragma unroll
  for (int nt = 0; nt < 4; ++nt) acc[nt] = (floatx4){0.f,0.f,0.f,0.f};

  for (int c4k = 0; c4k < 4; ++c4k) {         // K chunk of 128
    int kg0 = c4k * 128;
    #pragma unroll
    for (int p = 0; p < 8; ++p) {
      int i = p*256 + tid;
      int r = i >> 5, c = (i & 31) * 4;
      float4 xv = *(const float4*)&x[(size_t)(rt*64 + r)*DM + kg0 + c];
      uint2 pk;
      pk.x = (unsigned)f2bf(xv.x) | ((unsigned)f2bf(xv.y) << 16);
      pk.y = (unsigned)f2bf(xv.z) | ((unsigned)f2bf(xv.w) << 16);
      *(uint2*)&u.xb[r][c] = pk;
    }
    #pragma unroll
    for (int p = 0; p < 4; ++p) {
      int k0 = p*32 + wv*8;
      unsigned short tmp[8];
      #pragma unroll
      for (int jj = 0; jj < 8; ++jj)
        tmp[jj] = f2bf(W[(kg0 + k0 + jj)*DH + ln]);
      uint4 pk;
      pk.x = tmp[0] | ((unsigned)tmp[1] << 16);
      pk.y = tmp[2] | ((unsigned)tmp[3] << 16);
      pk.z = tmp[4] | ((unsigned)tmp[5] << 16);
      pk.w = tmp[6] | ((unsigned)tmp[7] << 16);
      *(uint4*)&u.wbt[ln][k0] = pk;
    }
    __syncthreads();

    short8 afr[4];
    #pragma unroll
    for (int kc = 0; kc < 4; ++kc)
      afr[kc] = *(const short8*)&u.xb[wv*16 + l15][kc*32 + q4*8];
    #pragma unroll
    for (int nt = 0; nt < 4; ++nt) {
      floatx4 c = acc[nt];
      #pragma unroll
      for (int kc = 0; kc < 4; ++kc) {
        short8 bfr = *(const short8*)&u.wbt[nt*16 + l15][kc*32 + q4*8];
        c = __builtin_amdgcn_mfma_f32_16x16x32_bf16(afr[kc], bfr, c, 0,0,0);
      }
      acc[nt] = c;
    }
    __syncthreads();
  }

  #pragma unroll
  for (int nt = 0; nt < 4; ++nt) {
    int col = nt*16 + l15;
    float bias = 0.f;
    if (proj == 0) bias = bk1[n*DH + col];
    else if (proj == 1) bias = bk2[n*DH + col];
    else if (proj == 2) bias = bq[n*DH + col];
    #pragma unroll
    for (int r = 0; r < 4; ++r) {
      int row = rt*64 + wv*16 + q4*4 + r;
      int b = row >> 7, s = row & 127;
      size_t o = (size_t)((b*NH + n)*TS + s)*DH + col;
      float v = acc[nt][r] + bias;
      switch (proj) {
        case 0: ((unsigned short*)(ws + OFS_K1B))[o] = f2bf(v); break;
        case 1: ((unsigned short*)(ws + OFS_K2B))[o] = f2bf(v); break;
        case 2: ws[OFS_Q + o] = v; break;
        case 3: ws[OFS_VA + o] = v; break;
        default: ws[OFS_VB + o] = v; break;
      }
    }
  }
}

// ---------------------------------------------------------------------------
// attn body (one head, one q; q>=2 guaranteed by caller). Identical
// arithmetic to the R9 champion; only change: z row segment goes to LDS
// zrow[n*DH+h] instead of global. Back-to-back calls race-free: next call's
// head writes (Cp, Bh) are LDS-disjoint from this call's tail reads
// (zpart, dpart), and its first barrier orders zrow/Bh reuse.
// ---------------------------------------------------------------------------
__device__ __forceinline__ void attn_body(
    AttnS& u, float* zrow, const float* __restrict__ ws,
    const float* __restrict__ bv12, int bn, int q, int tid, int wv, int ln,
    int q4, int l15)
{
  int n = bn & 7;

  const unsigned short* k1g = (const unsigned short*)(ws + OFS_K1B) + (size_t)bn*TS*DH;
  const unsigned short* k2g = (const unsigned short*)(ws + OFS_K2B) + (size_t)bn*TS*DH;
  const float* qg  = ws + OFS_Q  + ((size_t)bn*TS + q)*DH;
  const float* vag = ws + OFS_VA + (size_t)bn*TS*DH;
  const float* vbg = ws + OFS_VB + (size_t)bn*TS*DH;

  short8 afr[2][2];                             // k1 frags, s-tiles {wv, wv+4}
  #pragma unroll
  for (int si2 = 0; si2 < 2; ++si2) {
    int m = (wv + 4*si2)*16 + l15;
    afr[si2][0] = *(const short8*)&k1g[m*DH + q4*8];
    afr[si2][1] = *(const short8*)&k1g[m*DH + q4*8 + 32];
  }

  ((float*)u.Cp)[tid] = 0.f; ((float*)u.Cp)[tid + 256] = 0.f;

  int T = (q + 15) >> 4;                        // active t-tiles (t < q)
  for (int i = tid; i < T*128; i += 256) {      // build Bh rows [0,16T)
    int r = i >> 3, c = (i & 7) * 8;
    short8 kv = *(const short8*)&k2g[r*DH + c];
    float4 q0 = *(const float4*)&qg[c];
    float4 q1 = *(const float4*)&qg[c + 4];
    unsigned short o8[8];
    o8[0] = f2bf(bf2f(kv[0]) * q0.x); o8[1] = f2bf(bf2f(kv[1]) * q0.y);
    o8[2] = f2bf(bf2f(kv[2]) * q0.z); o8[3] = f2bf(bf2f(kv[3]) * q0.w);
    o8[4] = f2bf(bf2f(kv[4]) * q1.x); o8[5] = f2bf(bf2f(kv[5]) * q1.y);
    o8[6] = f2bf(bf2f(kv[6]) * q1.z); o8[7] = f2bf(bf2f(kv[7]) * q1.w);
    uint4 pk;
    pk.x = o8[0] | ((unsigned)o8[1] << 16);
    pk.y = o8[2] | ((unsigned)o8[3] << 16);
    pk.z = o8[4] | ((unsigned)o8[5] << 16);
    pk.w = o8[6] | ((unsigned)o8[7] << 16);
    *(uint4*)&u.Bh[r][c] = pk;
  }
  __syncthreads();

  float rsum[2][4] = {{0.f,0.f,0.f,0.f},{0.f,0.f,0.f,0.f}};
  for (int tt = wv; tt < T; ++tt) {             // wave-uniform bounds
    int tg = tt*16 + l15;
    short8 b0 = *(const short8*)&u.Bh[tg][q4*8];
    short8 b1 = *(const short8*)&u.Bh[tg][q4*8 + 32];
    float csum = 0.f;
    #pragma unroll
    for (int si2 = 0; si2 < 2; ++si2) {
      int si = wv + 4*si2;
      if (si > tt || 16*si >= q - 1) continue;  // wave-uniform skip
      floatx4 c = (floatx4){0.f,0.f,0.f,0.f};
      c = __builtin_amdgcn_mfma_f32_16x16x32_bf16(afr[si2][0], b0, c, 0,0,0);
      c = __builtin_amdgcn_mfma_f32_16x16x32_bf16(afr[si2][1], b1, c, 0,0,0);
      #pragma unroll
      for (int rg = 0; rg < 4; ++rg) {          // C: row(s)=q4*4+rg, col(t)=l15
        int s = si*16 + q4*4 + rg;
        float e = (s < tg && tg < q) ? __expf(c[rg] * 0.015625f) : 0.f;
        rsum[si2][rg] += e;
        csum += e;
      }
    }
    csum += __shfl_xor(csum, 16, 64);           // reduce over q4 groups
    csum += __shfl_xor(csum, 32, 64);
    if (q4 == 0) u.Cp[wv][tg] = csum;
  }
  #pragma unroll
  for (int si2 = 0; si2 < 2; ++si2)
    #pragma unroll
    for (int rg = 0; rg < 4; ++rg) {            // row sums: reduce over l15
      float v = rsum[si2][rg];
      v += __shfl_xor(v, 1, 64); v += __shfl_xor(v, 2, 64);
      v += __shfl_xor(v, 4, 64); v += __shfl_xor(v, 8, 64);
      if (l15 == 0) u.Rs[(wv + 4*si2)*16 + q4*4 + rg] = v;
    }
  __syncthreads();

  if (tid < 128) u.Cs[tid] = u.Cp[0][tid] + u.Cp[1][tid]
                           + u.Cp[2][tid] + u.Cp[3][tid];
  __syncthreads();

  int g = wv, h = ln;                           // z numerator + D partials
  float acc = 0.f, dp = 0.f;
  int imax = (q + 3) >> 2;
  for (int i = 0; i < imax; ++i) {
    int s = g + 4*i;
    float rv = u.Rs[s], cv = u.Cs[s];
    acc = fmaf(rv, vag[s*DH + h], acc);
    acc = fmaf(cv, vbg[s*DH + h], acc);
    dp += rv;
  }
  u.zpart[g][h] = acc;
  if (ln == 0) u.dpart[g] = dp;
  __syncthreads();

  if (tid < 64) {
    float D = u.dpart[0] + u.dpart[1] + u.dpart[2] + u.dpart[3];
    float zv = (u.zpart[0][tid] + u.zpart[1][tid]
              + u.zpart[2][tid] + u.zpart[3][tid]) / D
               + bv12[n*DH + tid];
    zrow[n*DH + tid] = zv;                      // LDS, not global
  }
}

// ---------------------------------------------------------------------------
// Fused attn+out: one block per (b,q) = 256 blocks (1/CU, all co-resident).
// Loop over 8 heads filling zrow[512] in LDS, then the Wo GEMM for this row
// in-block (float4 Wo loads, wave-split K, LDS reduce). Removes one kernel
// boundary and the z global round-trip vs the R9 3-kernel structure.
// ---------------------------------------------------------------------------
__global__ __launch_bounds__(256, 4) void attn_out_kernel(
    const float* __restrict__ ws, const float* __restrict__ bv12,
    const float* __restrict__ Wo, const float* __restrict__ bo,
    float* __restrict__ out)
{
  __shared__ AttnS u;
  __shared__ __align__(16) float zrow[DM];      // 2 KB
  __shared__ __align__(16) float zop[4][DM];    // 8 KB

  int q = blockIdx.x & 127;
  int b = blockIdx.x >> 7;
  int tid = threadIdx.x;
  int wv = tid >> 6, ln = tid & 63, q4 = ln >> 4, l15 = ln & 15;
  float* orow = out + (size_t)(b*TS + q)*DM;

  if (q < 2) {                                  // all heads: z=0 -> out = bias
    orow[tid]       = bo[tid];
    orow[tid + 256] = bo[tid + 256];
    return;
  }

  #pragma unroll 1
  for (int n = 0; n < NH; ++n)
    attn_body(u, zrow, ws, bv12, b*NH + n, q, tid, wv, ln, q4, l15);
  __syncthreads();                              // zrow complete

  // GEMM: orow[c] = sum_k zrow[k] * Wo[k][c] + bo[c].
  // Wave wv owns k in [wv*128, +128); pass p covers cols [p*256, +256);
  // lane handles 4 consecutive cols -> float4 loads, 1 KB/wave-inst.
  #pragma unroll
  for (int p = 0; p < 2; ++p) {
    int c = p*256 + ln*4;
    float4 a = {0.f, 0.f, 0.f, 0.f};
    const float* wp = Wo + (size_t)(wv*128)*DM + c;
    #pragma unroll 8
    for (int kk = 0; kk < 128; ++kk) {
      float4 w = *(const float4*)(wp + (size_t)kk*DM);
      float zk = zrow[wv*128 + kk];             // wave-uniform broadcast
      a.x = fmaf(zk, w.x, a.x); a.y = fmaf(zk, w.y, a.y);
      a.z = fmaf(zk, w.z, a.z); a.w = fmaf(zk, w.w, a.w);
    }
    *(float4*)&zop[wv][c] = a;
  }
  __syncthreads();

  #pragma unroll
  for (int p = 0; p < 2; ++p) {
    int c = p*256 + tid;
    orow[c] = zop[0][c] + zop[1][c] + zop[2][c] + zop[3][c] + bo[c];
  }
}

extern "C" void kernel_launch(void* const* d_in, const int* in_sizes, int n_in,
                              void* d_out, int out_size, void* d_ws, size_t ws_size,
                              hipStream_t stream)
{
  const float* x    = (const float*)d_in[0];
  const float* Wk1  = (const float*)d_in[1];
  const float* Wk2  = (const float*)d_in[2];
  const float* Wq   = (const float*)d_in[3];
  const float* Wv12 = (const float*)d_in[4];
  const float* Wo   = (const float*)d_in[5];
  const float* bk1  = (const float*)d_in[6];
  const float* bk2  = (const float*)d_in[7];
  const float* bq   = (const float*)d_in[8];
  const float* bv12 = (const float*)d_in[9];
  const float* bo   = (const float*)d_in[10];
  float* out = (float*)d_out;
  float* ws  = (float*)d_ws;    // 2.1 MB used

  proj_kernel<<<N_PROJ_JOBS, 256, 0, stream>>>(x, Wk1, Wk2, Wq, Wv12,
                                               bk1, bk2, bq, ws);
  attn_out_kernel<<<BS*TS, 256, 0, stream>>>(ws, bv12, Wo, bo, out);
}

// Round 11
// 113.760 us; speedup vs baseline: 1.3439x; 1.3439x over previous
//
#include <hip/hip_runtime.h>

#define BS 2
#define TS 128
#define DM 512
#define NH 8
#define DH 64
#define BN (BS*NH)            // 16

typedef __attribute__((ext_vector_type(8))) short short8;
typedef __attribute__((ext_vector_type(4))) float floatx4;

// ws layout (float element offsets). Total 5*SEG*4B = 2.6 MB.
#define SEG (BN*TS*DH)                  // 131072
#define OFS_Q    0                      // fp32 [bn][s][h] (+bias)
#define OFS_VA   SEG                    // fp32 [bn][s][h]
#define OFS_VB   (2*SEG)                // fp32 [bn][s][h]
#define OFS_K1B  (3*SEG)                // bf16 [bn][s][h] (+bias), SEG/2 floats
#define OFS_K2B  (3*SEG + SEG/2)        // bf16 [bn][s][h] (+bias)
#define OFS_Z    (4*SEG)                // fp32 [b*TS+q][n*DH+h]  (256 x 512)

#define N_PROJ_JOBS 160
#define N_ATTN_JOBS 1024                // (bn, j) pairs; each does q=j and q=127-j
#define N_OUT_JOBS  1024                // (row-pair, col-tile)

__device__ __forceinline__ unsigned short f2bf(float x) {
  unsigned u = __float_as_uint(x);
  u += 0x7fff + ((u >> 16) & 1);        // round-to-nearest-even
  return (unsigned short)(u >> 16);
}
__device__ __forceinline__ float bf2f(short v) {
  return __uint_as_float(((unsigned)(unsigned short)v) << 16);
}

struct __align__(16) ProjS { short xb[64][136]; short wbt[64][136]; }; // 34.8KB
struct __align__(16) AttnS {
  short Bh[128][72]; float Rs[128]; float Cp[4][128];
  float Cs[128]; float zpart[4][64]; float dpart[4];                   // 22.5KB
};
struct __align__(16) OutS  { float zt[2][520]; float zop[4][2][64]; }; // 6.2KB

// ---------------------------------------------------------------------------
// proj body: identical to the R9 champion (112.1us config).
// ---------------------------------------------------------------------------
__device__ __forceinline__ void proj_body(
    ProjS& u, const float* __restrict__ x,   const float* __restrict__ Wk1,
    const float* __restrict__ Wk2, const float* __restrict__ Wq,
    const float* __restrict__ Wv12,const float* __restrict__ bk1,
    const float* __restrict__ bk2, const float* __restrict__ bq,
    float* __restrict__ ws, int job, int tid, int wv, int ln, int q4, int l15)
{
  int t = job;
  int rt = t & 3; t >>= 2;
  int n  = t & 7; t >>= 3;
  int proj = t;                       // 0..4

  const float* W;
  switch (proj) {
    case 0:  W = Wk1 + n*DM*DH;  break;
    case 1:  W = Wk2 + n*DM*DH;  break;
    case 2:  W = Wq  + n*DM*DH;  break;
    case 3:  W = Wv12 + n*2*DM*DH;  break;
    default: W = Wv12 + n*2*DM*DH + DM*DH;  break;
  }

  floatx4 acc[4];
  #pragma unroll
  for (int nt = 0; nt < 4; ++nt) acc[nt] = (floatx4){0.f,0.f,0.f,0.f};

  for (int c4k = 0; c4k < 4; ++c4k) {         // K chunk of 128
    int kg0 = c4k * 128;
    #pragma unroll
    for (int p = 0; p < 8; ++p) {
      int i = p*256 + tid;
      int r = i >> 5, c = (i & 31) * 4;
      float4 xv = *(const float4*)&x[(size_t)(rt*64 + r)*DM + kg0 + c];
      uint2 pk;
      pk.x = (unsigned)f2bf(xv.x) | ((unsigned)f2bf(xv.y) << 16);
      pk.y = (unsigned)f2bf(xv.z) | ((unsigned)f2bf(xv.w) << 16);
      *(uint2*)&u.xb[r][c] = pk;
    }
    #pragma unroll
    for (int p = 0; p < 4; ++p) {
      int k0 = p*32 + wv*8;
      unsigned short tmp[8];
      #pragma unroll
      for (int jj = 0; jj < 8; ++jj)
        tmp[jj] = f2bf(W[(kg0 + k0 + jj)*DH + ln]);
      uint4 pk;
      pk.x = tmp[0] | ((unsigned)tmp[1] << 16);
      pk.y = tmp[2] | ((unsigned)tmp[3] << 16);
      pk.z = tmp[4] | ((unsigned)tmp[5] << 16);
      pk.w = tmp[6] | ((unsigned)tmp[7] << 16);
      *(uint4*)&u.wbt[ln][k0] = pk;
    }
    __syncthreads();

    short8 afr[4];
    #pragma unroll
    for (int kc = 0; kc < 4; ++kc)
      afr[kc] = *(const short8*)&u.xb[wv*16 + l15][kc*32 + q4*8];
    #pragma unroll
    for (int nt = 0; nt < 4; ++nt) {
      floatx4 c = acc[nt];
      #pragma unroll
      for (int kc = 0; kc < 4; ++kc) {
        short8 bfr = *(const short8*)&u.wbt[nt*16 + l15][kc*32 + q4*8];
        c = __builtin_amdgcn_mfma_f32_16x16x32_bf16(afr[kc], bfr, c, 0,0,0);
      }
      acc[nt] = c;
    }
    __syncthreads();
  }

  #pragma unroll
  for (int nt = 0; nt < 4; ++nt) {
    int col = nt*16 + l15;
    float bias = 0.f;
    if (proj == 0) bias = bk1[n*DH + col];
    else if (proj == 1) bias = bk2[n*DH + col];
    else if (proj == 2) bias = bq[n*DH + col];
    #pragma unroll
    for (int r = 0; r < 4; ++r) {
      int row = rt*64 + wv*16 + q4*4 + r;
      int b = row >> 7, s = row & 127;
      size_t o = (size_t)((b*NH + n)*TS + s)*DH + col;
      float v = acc[nt][r] + bias;
      switch (proj) {
        case 0: ((unsigned short*)(ws + OFS_K1B))[o] = f2bf(v); break;
        case 1: ((unsigned short*)(ws + OFS_K2B))[o] = f2bf(v); break;
        case 2: ws[OFS_Q + o] = v; break;
        case 3: ws[OFS_VA + o] = v; break;
        default: ws[OFS_VB + o] = v; break;
      }
    }
  }
}

// ---------------------------------------------------------------------------
// attn body (one q). R11: ONLY change vs R9 champion — wave s-tile map is
// {wv, 7-wv} (was {wv, wv+4}). With the causal skip, per-wave tile-MFMA
// counts at T=8 go 12/10/8/6 -> 9/9/9/9; barrier waits on the max wave.
// Coverage of s-tiles 0..7 unchanged; map is q-independent (afr hoist OK).
// ---------------------------------------------------------------------------
__device__ __forceinline__ void attn_body(
    AttnS& u, const float* __restrict__ ws, const float* __restrict__ bv12,
    float* __restrict__ zb, int bn, int q, int tid, int wv, int ln,
    int q4, int l15, const int (&si_tab)[2], const short8 (&afr)[2][2])
{
  int b = bn >> 3, n = bn & 7;

  if (q < 2) {                        // z=0 -> out row is bias only
    if (tid < 64) zb[(size_t)(b*TS + q)*DM + n*DH + tid] = 0.f;
    return;
  }

  const unsigned short* k2g = (const unsigned short*)(ws + OFS_K2B) + (size_t)bn*TS*DH;
  const float* qg  = ws + OFS_Q  + ((size_t)bn*TS + q)*DH;
  const float* vag = ws + OFS_VA + (size_t)bn*TS*DH;
  const float* vbg = ws + OFS_VB + (size_t)bn*TS*DH;

  ((float*)u.Cp)[tid] = 0.f; ((float*)u.Cp)[tid + 256] = 0.f;

  int T = (q + 15) >> 4;                        // active t-tiles (t < q)
  for (int i = tid; i < T*128; i += 256) {      // build Bh rows [0,16T)
    int r = i >> 3, c = (i & 7) * 8;
    short8 kv = *(const short8*)&k2g[r*DH + c];
    float4 q0 = *(const float4*)&qg[c];
    float4 q1 = *(const float4*)&qg[c + 4];
    unsigned short o8[8];
    o8[0] = f2bf(bf2f(kv[0]) * q0.x); o8[1] = f2bf(bf2f(kv[1]) * q0.y);
    o8[2] = f2bf(bf2f(kv[2]) * q0.z); o8[3] = f2bf(bf2f(kv[3]) * q0.w);
    o8[4] = f2bf(bf2f(kv[4]) * q1.x); o8[5] = f2bf(bf2f(kv[5]) * q1.y);
    o8[6] = f2bf(bf2f(kv[6]) * q1.z); o8[7] = f2bf(bf2f(kv[7]) * q1.w);
    uint4 pk;
    pk.x = o8[0] | ((unsigned)o8[1] << 16);
    pk.y = o8[2] | ((unsigned)o8[3] << 16);
    pk.z = o8[4] | ((unsigned)o8[5] << 16);
    pk.w = o8[6] | ((unsigned)o8[7] << 16);
    *(uint4*)&u.Bh[r][c] = pk;
  }
  __syncthreads();

  float rsum[2][4] = {{0.f,0.f,0.f,0.f},{0.f,0.f,0.f,0.f}};
  for (int tt = wv; tt < T; ++tt) {             // wave-uniform bounds
    int tg = tt*16 + l15;
    short8 b0 = *(const short8*)&u.Bh[tg][q4*8];
    short8 b1 = *(const short8*)&u.Bh[tg][q4*8 + 32];
    float csum = 0.f;
    #pragma unroll
    for (int si2 = 0; si2 < 2; ++si2) {
      int si = si_tab[si2];
      if (si > tt || 16*si >= q - 1) continue;  // wave-uniform skip
      floatx4 c = (floatx4){0.f,0.f,0.f,0.f};
      c = __builtin_amdgcn_mfma_f32_16x16x32_bf16(afr[si2][0], b0, c, 0,0,0);
      c = __builtin_amdgcn_mfma_f32_16x16x32_bf16(afr[si2][1], b1, c, 0,0,0);
      #pragma unroll
      for (int rg = 0; rg < 4; ++rg) {          // C: row(s)=q4*4+rg, col(t)=l15
        int s = si*16 + q4*4 + rg;
        float e = (s < tg && tg < q) ? __expf(c[rg] * 0.015625f) : 0.f;
        rsum[si2][rg] += e;
        csum += e;
      }
    }
    csum += __shfl_xor(csum, 16, 64);           // reduce over q4 groups
    csum += __shfl_xor(csum, 32, 64);
    if (q4 == 0) u.Cp[wv][tg] = csum;
  }
  #pragma unroll
  for (int si2 = 0; si2 < 2; ++si2)
    #pragma unroll
    for (int rg = 0; rg < 4; ++rg) {            // row sums: reduce over l15
      float v = rsum[si2][rg];
      v += __shfl_xor(v, 1, 64); v += __shfl_xor(v, 2, 64);
      v += __shfl_xor(v, 4, 64); v += __shfl_xor(v, 8, 64);
      if (l15 == 0) u.Rs[si_tab[si2]*16 + q4*4 + rg] = v;
    }
  __syncthreads();

  if (tid < 128) u.Cs[tid] = u.Cp[0][tid] + u.Cp[1][tid]
                           + u.Cp[2][tid] + u.Cp[3][tid];
  __syncthreads();

  int g = wv, h = ln;                           // z numerator + D partials
  float acc = 0.f, dp = 0.f;
  int imax = (q + 3) >> 2;
  for (int i = 0; i < imax; ++i) {
    int s = g + 4*i;
    float rv = u.Rs[s], cv = u.Cs[s];
    acc = fmaf(rv, vag[s*DH + h], acc);
    acc = fmaf(cv, vbg[s*DH + h], acc);
    dp += rv;
  }
  u.zpart[g][h] = acc;
  if (ln == 0) u.dpart[g] = dp;
  __syncthreads();

  if (tid < 64) {
    float D = u.dpart[0] + u.dpart[1] + u.dpart[2] + u.dpart[3];
    float zv = (u.zpart[0][tid] + u.zpart[1][tid]
              + u.zpart[2][tid] + u.zpart[3][tid]) / D
               + bv12[n*DH + tid];
    zb[(size_t)(b*TS + q)*DM + n*DH + tid] = zv;
  }
}

__device__ __forceinline__ void attn_pair(
    AttnS& u, const float* __restrict__ ws, const float* __restrict__ bv12,
    float* __restrict__ zb, int job, int tid, int wv, int ln, int q4, int l15)
{
  int bn = job >> 6, j = job & 63;              // q pair {j, 127-j}: T sums ~8
  const unsigned short* k1g =
      (const unsigned short*)(ws + OFS_K1B) + (size_t)bn*TS*DH;
  int si_tab[2] = { wv, 7 - wv };               // balanced partition of 0..7
  short8 afr[2][2];                             // k1 frags are q-independent
  #pragma unroll
  for (int si2 = 0; si2 < 2; ++si2) {
    int m = si_tab[si2]*16 + l15;
    afr[si2][0] = *(const short8*)&k1g[m*DH + q4*8];
    afr[si2][1] = *(const short8*)&k1g[m*DH + q4*8 + 32];
  }
  attn_body(u, ws, bv12, zb, bn, j,       tid, wv, ln, q4, l15, si_tab, afr);
  attn_body(u, ws, bv12, zb, bn, 127 - j, tid, wv, ln, q4, l15, si_tab, afr);
}

// ---------------------------------------------------------------------------
// out body: identical to the R9 champion (112.1us config).
// ---------------------------------------------------------------------------
__device__ __forceinline__ void out_job(
    OutS& u, const float* __restrict__ zb, const float* __restrict__ Wo,
    const float* __restrict__ bo, float* __restrict__ out,
    int job, int tid, int wv, int ln)
{
  int r0 = (job >> 3) * 2;                      // 128 row-pairs
  int c0 = (job & 7) * 64;                      // 8 col-tiles
  {
    int r = tid >> 7, c4 = (tid & 127) * 4;     // 256 float4 = 2x512 floats
    *(float4*)&u.zt[r][c4] = *(const float4*)&zb[(size_t)(r0 + r)*DM + c4];
  }
  __syncthreads();

  float a0 = 0.f, a1 = 0.f;
  const float* wp = Wo + (size_t)(wv*128)*DM + c0 + ln;
  #pragma unroll 8
  for (int kk = 0; kk < 128; ++kk) {
    float w = wp[(size_t)kk*DM];
    a0 = fmaf(u.zt[0][wv*128 + kk], w, a0);
    a1 = fmaf(u.zt[1][wv*128 + kk], w, a1);
  }
  u.zop[wv][0][ln] = a0;
  u.zop[wv][1][ln] = a1;
  __syncthreads();

  if (tid < 128) {
    int r = tid >> 6, cc = tid & 63;
    float v = u.zop[0][r][cc] + u.zop[1][r][cc]
            + u.zop[2][r][cc] + u.zop[3][r][cc] + bo[c0 + cc];
    out[(size_t)(r0 + r)*DM + c0 + cc] = v;
  }
}

// ---------------------------------------------------------------------------
// Standalone kernels (3-kernel path; cooperative fusion 3x slower (R5),
// attn+out block fusion +40us from lost TLP (R10)).
// ---------------------------------------------------------------------------
__global__ __launch_bounds__(256, 4) void proj_kernel(
    const float* __restrict__ x,   const float* __restrict__ Wk1,
    const float* __restrict__ Wk2, const float* __restrict__ Wq,
    const float* __restrict__ Wv12,const float* __restrict__ bk1,
    const float* __restrict__ bk2, const float* __restrict__ bq,
    float* __restrict__ ws)
{
  __shared__ ProjS u;
  int tid = threadIdx.x;
  int wv = tid >> 6, ln = tid & 63, q4 = ln >> 4, l15 = ln & 15;
  proj_body(u, x, Wk1, Wk2, Wq, Wv12, bk1, bk2, bq, ws,
            blockIdx.x, tid, wv, ln, q4, l15);
}

__global__ __launch_bounds__(256, 4) void attn_kernel(
    const float* __restrict__ ws, const float* __restrict__ bv12,
    float* __restrict__ zb)
{
  __shared__ AttnS u;
  int tid = threadIdx.x;
  int wv = tid >> 6, ln = tid & 63, q4 = ln >> 4, l15 = ln & 15;
  attn_pair(u, ws, bv12, zb, blockIdx.x, tid, wv, ln, q4, l15);
}

__global__ __launch_bounds__(256, 4) void out_kernel(
    const float* __restrict__ zb, const float* __restrict__ Wo,
    const float* __restrict__ bo, float* __restrict__ out)
{
  __shared__ OutS u;
  int tid = threadIdx.x;
  int wv = tid >> 6, ln = tid & 63;
  out_job(u, zb, Wo, bo, out, blockIdx.x, tid, wv, ln);
}

extern "C" void kernel_launch(void* const* d_in, const int* in_sizes, int n_in,
                              void* d_out, int out_size, void* d_ws, size_t ws_size,
                              hipStream_t stream)
{
  const float* x    = (const float*)d_in[0];
  const float* Wk1  = (const float*)d_in[1];
  const float* Wk2  = (const float*)d_in[2];
  const float* Wq   = (const float*)d_in[3];
  const float* Wv12 = (const float*)d_in[4];
  const float* Wo   = (const float*)d_in[5];
  const float* bk1  = (const float*)d_in[6];
  const float* bk2  = (const float*)d_in[7];
  const float* bq   = (const float*)d_in[8];
  const float* bv12 = (const float*)d_in[9];
  const float* bo   = (const float*)d_in[10];
  float* out = (float*)d_out;
  float* ws  = (float*)d_ws;    // 2.6 MB used

  proj_kernel<<<N_PROJ_JOBS, 256, 0, stream>>>(x, Wk1, Wk2, Wq, Wv12,
                                               bk1, bk2, bq, ws);
  attn_kernel<<<N_ATTN_JOBS, 256, 0, stream>>>(ws, bv12, ws + OFS_Z);
  out_kernel<<<N_OUT_JOBS, 256, 0, stream>>>(ws + OFS_Z, Wo, bo, out);
}

// Round 12
// 111.823 us; speedup vs baseline: 1.3672x; 1.0173x over previous
//
#include <hip/hip_runtime.h>

#define BS 2
#define TS 128
#define DM 512
#define NH 8
#define DH 64
#define BN (BS*NH)            // 16

typedef __attribute__((ext_vector_type(8))) short short8;
typedef __attribute__((ext_vector_type(4))) float floatx4;

// ws layout (float element offsets). Total 5*SEG*4B = 2.6 MB.
#define SEG (BN*TS*DH)                  // 131072
#define OFS_Q    0                      // fp32 [bn][s][h] (+bias)
#define OFS_VA   SEG                    // fp32 [bn][s][h]
#define OFS_VB   (2*SEG)                // fp32 [bn][s][h]
#define OFS_K1B  (3*SEG)                // bf16 [bn][s][h] (+bias), SEG/2 floats
#define OFS_K2B  (3*SEG + SEG/2)        // bf16 [bn][s][h] (+bias)
#define OFS_Z    (4*SEG)                // fp32 [b*TS+q][n*DH+h]  (256 x 512)

#define N_PROJ_JOBS 160
#define N_ATTN_JOBS 1024                // (bn, j) pairs; each does q=j and q=127-j
#define N_OUT_JOBS  1024                // (row-pair, col-tile)

__device__ __forceinline__ unsigned short f2bf(float x) {
  unsigned u = __float_as_uint(x);
  u += 0x7fff + ((u >> 16) & 1);        // round-to-nearest-even
  return (unsigned short)(u >> 16);
}
__device__ __forceinline__ float bf2f(short v) {
  return __uint_as_float(((unsigned)(unsigned short)v) << 16);
}

// R11 post-mortem -> R12: wave-balance change was null (+1.7us, noise);
// reverted to the exact R9 champion source (112.1us). Session ledger:
// occupancy split -1.8 (noise), boundary fusion +40, cooperative +250,
// balance +1.7 -> structure is at its practical floor: ~82us harness fills
// (80-82% HBM, memory-bound, unreachable) + ~30us launch/latency-bound
// kernels (~3 GFLOP total, L2-resident).
struct __align__(16) ProjS { short xb[64][136]; short wbt[64][136]; }; // 34.8KB
struct __align__(16) AttnS {
  short Bh[128][72]; float Rs[128]; float Cp[4][128];
  float Cs[128]; float zpart[4][64]; float dpart[4];                   // 22.5KB
};
struct __align__(16) OutS  { float zt[2][520]; float zop[4][2][64]; }; // 6.2KB

// ---------------------------------------------------------------------------
// proj body: one (proj, n, rowtile) job. K chunked 4x128 -> 34.8 KB LDS.
// ---------------------------------------------------------------------------
__device__ __forceinline__ void proj_body(
    ProjS& u, const float* __restrict__ x,   const float* __restrict__ Wk1,
    const float* __restrict__ Wk2, const float* __restrict__ Wq,
    const float* __restrict__ Wv12,const float* __restrict__ bk1,
    const float* __restrict__ bk2, const float* __restrict__ bq,
    float* __restrict__ ws, int job, int tid, int wv, int ln, int q4, int l15)
{
  int t = job;
  int rt = t & 3; t >>= 2;
  int n  = t & 7; t >>= 3;
  int proj = t;                       // 0..4

  const float* W;
  switch (proj) {
    case 0:  W = Wk1 + n*DM*DH;  break;
    case 1:  W = Wk2 + n*DM*DH;  break;
    case 2:  W = Wq  + n*DM*DH;  break;
    case 3:  W = Wv12 + n*2*DM*DH;  break;
    default: W = Wv12 + n*2*DM*DH + DM*DH;  break;
  }

  floatx4 acc[4];
  #pragma unroll
  for (int nt = 0; nt < 4; ++nt) acc[nt] = (floatx4){0.f,0.f,0.f,0.f};

  for (int c4k = 0; c4k < 4; ++c4k) {         // K chunk of 128
    int kg0 = c4k * 128;
    #pragma unroll
    for (int p = 0; p < 8; ++p) {
      int i = p*256 + tid;
      int r = i >> 5, c = (i & 31) * 4;
      float4 xv = *(const float4*)&x[(size_t)(rt*64 + r)*DM + kg0 + c];
      uint2 pk;
      pk.x = (unsigned)f2bf(xv.x) | ((unsigned)f2bf(xv.y) << 16);
      pk.y = (unsigned)f2bf(xv.z) | ((unsigned)f2bf(xv.w) << 16);
      *(uint2*)&u.xb[r][c] = pk;
    }
    #pragma unroll
    for (int p = 0; p < 4; ++p) {
      int k0 = p*32 + wv*8;
      unsigned short tmp[8];
      #pragma unroll
      for (int jj = 0; jj < 8; ++jj)
        tmp[jj] = f2bf(W[(kg0 + k0 + jj)*DH + ln]);
      uint4 pk;
      pk.x = tmp[0] | ((unsigned)tmp[1] << 16);
      pk.y = tmp[2] | ((unsigned)tmp[3] << 16);
      pk.z = tmp[4] | ((unsigned)tmp[5] << 16);
      pk.w = tmp[6] | ((unsigned)tmp[7] << 16);
      *(uint4*)&u.wbt[ln][k0] = pk;
    }
    __syncthreads();

    short8 afr[4];
    #pragma unroll
    for (int kc = 0; kc < 4; ++kc)
      afr[kc] = *(const short8*)&u.xb[wv*16 + l15][kc*32 + q4*8];
    #pragma unroll
    for (int nt = 0; nt < 4; ++nt) {
      floatx4 c = acc[nt];
      #pragma unroll
      for (int kc = 0; kc < 4; ++kc) {
        short8 bfr = *(const short8*)&u.wbt[nt*16 + l15][kc*32 + q4*8];
        c = __builtin_amdgcn_mfma_f32_16x16x32_bf16(afr[kc], bfr, c, 0,0,0);
      }
      acc[nt] = c;
    }
    __syncthreads();
  }

  #pragma unroll
  for (int nt = 0; nt < 4; ++nt) {
    int col = nt*16 + l15;
    float bias = 0.f;
    if (proj == 0) bias = bk1[n*DH + col];
    else if (proj == 1) bias = bk2[n*DH + col];
    else if (proj == 2) bias = bq[n*DH + col];
    #pragma unroll
    for (int r = 0; r < 4; ++r) {
      int row = rt*64 + wv*16 + q4*4 + r;
      int b = row >> 7, s = row & 127;
      size_t o = (size_t)((b*NH + n)*TS + s)*DH + col;
      float v = acc[nt][r] + bias;
      switch (proj) {
        case 0: ((unsigned short*)(ws + OFS_K1B))[o] = f2bf(v); break;
        case 1: ((unsigned short*)(ws + OFS_K2B))[o] = f2bf(v); break;
        case 2: ws[OFS_Q + o] = v; break;
        case 3: ws[OFS_VA + o] = v; break;
        default: ws[OFS_VB + o] = v; break;
      }
    }
  }
}

// ---------------------------------------------------------------------------
// attn body (one q). R9-champion version: wave s-tile map {wv, wv+4}.
// ---------------------------------------------------------------------------
__device__ __forceinline__ void attn_body(
    AttnS& u, const float* __restrict__ ws, const float* __restrict__ bv12,
    float* __restrict__ zb, int bn, int q, int tid, int wv, int ln,
    int q4, int l15, const short8 (&afr)[2][2])
{
  int b = bn >> 3, n = bn & 7;

  if (q < 2) {                        // z=0 -> out row is bias only
    if (tid < 64) zb[(size_t)(b*TS + q)*DM + n*DH + tid] = 0.f;
    return;
  }

  const unsigned short* k2g = (const unsigned short*)(ws + OFS_K2B) + (size_t)bn*TS*DH;
  const float* qg  = ws + OFS_Q  + ((size_t)bn*TS + q)*DH;
  const float* vag = ws + OFS_VA + (size_t)bn*TS*DH;
  const float* vbg = ws + OFS_VB + (size_t)bn*TS*DH;

  ((float*)u.Cp)[tid] = 0.f; ((float*)u.Cp)[tid + 256] = 0.f;

  int T = (q + 15) >> 4;                        // active t-tiles (t < q)
  for (int i = tid; i < T*128; i += 256) {      // build Bh rows [0,16T)
    int r = i >> 3, c = (i & 7) * 8;
    short8 kv = *(const short8*)&k2g[r*DH + c];
    float4 q0 = *(const float4*)&qg[c];
    float4 q1 = *(const float4*)&qg[c + 4];
    unsigned short o8[8];
    o8[0] = f2bf(bf2f(kv[0]) * q0.x); o8[1] = f2bf(bf2f(kv[1]) * q0.y);
    o8[2] = f2bf(bf2f(kv[2]) * q0.z); o8[3] = f2bf(bf2f(kv[3]) * q0.w);
    o8[4] = f2bf(bf2f(kv[4]) * q1.x); o8[5] = f2bf(bf2f(kv[5]) * q1.y);
    o8[6] = f2bf(bf2f(kv[6]) * q1.z); o8[7] = f2bf(bf2f(kv[7]) * q1.w);
    uint4 pk;
    pk.x = o8[0] | ((unsigned)o8[1] << 16);
    pk.y = o8[2] | ((unsigned)o8[3] << 16);
    pk.z = o8[4] | ((unsigned)o8[5] << 16);
    pk.w = o8[6] | ((unsigned)o8[7] << 16);
    *(uint4*)&u.Bh[r][c] = pk;
  }
  __syncthreads();

  float rsum[2][4] = {{0.f,0.f,0.f,0.f},{0.f,0.f,0.f,0.f}};
  for (int tt = wv; tt < T; ++tt) {             // wave-uniform bounds
    int tg = tt*16 + l15;
    short8 b0 = *(const short8*)&u.Bh[tg][q4*8];
    short8 b1 = *(const short8*)&u.Bh[tg][q4*8 + 32];
    float csum = 0.f;
    #pragma unroll
    for (int si2 = 0; si2 < 2; ++si2) {
      int si = wv + 4*si2;
      if (si > tt || 16*si >= q - 1) continue;  // wave-uniform skip
      floatx4 c = (floatx4){0.f,0.f,0.f,0.f};
      c = __builtin_amdgcn_mfma_f32_16x16x32_bf16(afr[si2][0], b0, c, 0,0,0);
      c = __builtin_amdgcn_mfma_f32_16x16x32_bf16(afr[si2][1], b1, c, 0,0,0);
      #pragma unroll
      for (int rg = 0; rg < 4; ++rg) {          // C: row(s)=q4*4+rg, col(t)=l15
        int s = si*16 + q4*4 + rg;
        float e = (s < tg && tg < q) ? __expf(c[rg] * 0.015625f) : 0.f;
        rsum[si2][rg] += e;
        csum += e;
      }
    }
    csum += __shfl_xor(csum, 16, 64);           // reduce over q4 groups
    csum += __shfl_xor(csum, 32, 64);
    if (q4 == 0) u.Cp[wv][tg] = csum;
  }
  #pragma unroll
  for (int si2 = 0; si2 < 2; ++si2)
    #pragma unroll
    for (int rg = 0; rg < 4; ++rg) {            // row sums: reduce over l15
      float v = rsum[si2][rg];
      v += __shfl_xor(v, 1, 64); v += __shfl_xor(v, 2, 64);
      v += __shfl_xor(v, 4, 64); v += __shfl_xor(v, 8, 64);
      if (l15 == 0) u.Rs[(wv + 4*si2)*16 + q4*4 + rg] = v;
    }
  __syncthreads();

  if (tid < 128) u.Cs[tid] = u.Cp[0][tid] + u.Cp[1][tid]
                           + u.Cp[2][tid] + u.Cp[3][tid];
  __syncthreads();

  int g = wv, h = ln;                           // z numerator + D partials
  float acc = 0.f, dp = 0.f;
  int imax = (q + 3) >> 2;
  for (int i = 0; i < imax; ++i) {
    int s = g + 4*i;
    float rv = u.Rs[s], cv = u.Cs[s];
    acc = fmaf(rv, vag[s*DH + h], acc);
    acc = fmaf(cv, vbg[s*DH + h], acc);
    dp += rv;
  }
  u.zpart[g][h] = acc;
  if (ln == 0) u.dpart[g] = dp;
  __syncthreads();

  if (tid < 64) {
    float D = u.dpart[0] + u.dpart[1] + u.dpart[2] + u.dpart[3];
    float zv = (u.zpart[0][tid] + u.zpart[1][tid]
              + u.zpart[2][tid] + u.zpart[3][tid]) / D
               + bv12[n*DH + tid];
    zb[(size_t)(b*TS + q)*DM + n*DH + tid] = zv;
  }
}

__device__ __forceinline__ void attn_pair(
    AttnS& u, const float* __restrict__ ws, const float* __restrict__ bv12,
    float* __restrict__ zb, int job, int tid, int wv, int ln, int q4, int l15)
{
  int bn = job >> 6, j = job & 63;              // q pair {j, 127-j}: T sums ~8
  const unsigned short* k1g =
      (const unsigned short*)(ws + OFS_K1B) + (size_t)bn*TS*DH;
  short8 afr[2][2];                             // k1 frags are q-independent
  #pragma unroll
  for (int si2 = 0; si2 < 2; ++si2) {
    int m = (wv + 4*si2)*16 + l15;
    afr[si2][0] = *(const short8*)&k1g[m*DH + q4*8];
    afr[si2][1] = *(const short8*)&k1g[m*DH + q4*8 + 32];
  }
  attn_body(u, ws, bv12, zb, bn, j,       tid, wv, ln, q4, l15, afr);
  attn_body(u, ws, bv12, zb, bn, 127 - j, tid, wv, ln, q4, l15, afr);
}

// ---------------------------------------------------------------------------
// out body: out[2 rows][64 cols] = z @ W_O + b_O, waves split K in quarters.
// ---------------------------------------------------------------------------
__device__ __forceinline__ void out_job(
    OutS& u, const float* __restrict__ zb, const float* __restrict__ Wo,
    const float* __restrict__ bo, float* __restrict__ out,
    int job, int tid, int wv, int ln)
{
  int r0 = (job >> 3) * 2;                      // 128 row-pairs
  int c0 = (job & 7) * 64;                      // 8 col-tiles
  {
    int r = tid >> 7, c4 = (tid & 127) * 4;     // 256 float4 = 2x512 floats
    *(float4*)&u.zt[r][c4] = *(const float4*)&zb[(size_t)(r0 + r)*DM + c4];
  }
  __syncthreads();

  float a0 = 0.f, a1 = 0.f;
  const float* wp = Wo + (size_t)(wv*128)*DM + c0 + ln;
  #pragma unroll 8
  for (int kk = 0; kk < 128; ++kk) {
    float w = wp[(size_t)kk*DM];
    a0 = fmaf(u.zt[0][wv*128 + kk], w, a0);
    a1 = fmaf(u.zt[1][wv*128 + kk], w, a1);
  }
  u.zop[wv][0][ln] = a0;
  u.zop[wv][1][ln] = a1;
  __syncthreads();

  if (tid < 128) {
    int r = tid >> 6, cc = tid & 63;
    float v = u.zop[0][r][cc] + u.zop[1][r][cc]
            + u.zop[2][r][cc] + u.zop[3][r][cc] + bo[c0 + cc];
    out[(size_t)(r0 + r)*DM + c0 + cc] = v;
  }
}

// ---------------------------------------------------------------------------
// Standalone kernels (3-kernel path; cooperative fusion 3x slower (R5),
// attn+out block fusion +40us from lost TLP (R10)).
// ---------------------------------------------------------------------------
__global__ __launch_bounds__(256, 4) void proj_kernel(
    const float* __restrict__ x,   const float* __restrict__ Wk1,
    const float* __restrict__ Wk2, const float* __restrict__ Wq,
    const float* __restrict__ Wv12,const float* __restrict__ bk1,
    const float* __restrict__ bk2, const float* __restrict__ bq,
    float* __restrict__ ws)
{
  __shared__ ProjS u;
  int tid = threadIdx.x;
  int wv = tid >> 6, ln = tid & 63, q4 = ln >> 4, l15 = ln & 15;
  proj_body(u, x, Wk1, Wk2, Wq, Wv12, bk1, bk2, bq, ws,
            blockIdx.x, tid, wv, ln, q4, l15);
}

__global__ __launch_bounds__(256, 4) void attn_kernel(
    const float* __restrict__ ws, const float* __restrict__ bv12,
    float* __restrict__ zb)
{
  __shared__ AttnS u;
  int tid = threadIdx.x;
  int wv = tid >> 6, ln = tid & 63, q4 = ln >> 4, l15 = ln & 15;
  attn_pair(u, ws, bv12, zb, blockIdx.x, tid, wv, ln, q4, l15);
}

__global__ __launch_bounds__(256, 4) void out_kernel(
    const float* __restrict__ zb, const float* __restrict__ Wo,
    const float* __restrict__ bo, float* __restrict__ out)
{
  __shared__ OutS u;
  int tid = threadIdx.x;
  int wv = tid >> 6, ln = tid & 63;
  out_job(u, zb, Wo, bo, out, blockIdx.x, tid, wv, ln);
}

extern "C" void kernel_launch(void* const* d_in, const int* in_sizes, int n_in,
                              void* d_out, int out_size, void* d_ws, size_t ws_size,
                              hipStream_t stream)
{
  const float* x    = (const float*)d_in[0];
  const float* Wk1  = (const float*)d_in[1];
  const float* Wk2  = (const float*)d_in[2];
  const float* Wq   = (const float*)d_in[3];
  const float* Wv12 = (const float*)d_in[4];
  const float* Wo   = (const float*)d_in[5];
  const float* bk1  = (const float*)d_in[6];
  const float* bk2  = (const float*)d_in[7];
  const float* bq   = (const float*)d_in[8];
  const float* bv12 = (const float*)d_in[9];
  const float* bo   = (const float*)d_in[10];
  float* out = (float*)d_out;
  float* ws  = (float*)d_ws;    // 2.6 MB used

  proj_kernel<<<N_PROJ_JOBS, 256, 0, stream>>>(x, Wk1, Wk2, Wq, Wv12,
                                               bk1, bk2, bq, ws);
  attn_kernel<<<N_ATTN_JOBS, 256, 0, stream>>>(ws, bv12, ws + OFS_Z);
  out_kernel<<<N_OUT_JOBS, 256, 0, stream>>>(ws + OFS_Z, Wo, bo, out);
}